// Round 8
// baseline (97.280 us; speedup 1.0000x reference)
//
#include <hip/hip_runtime.h>

// DotProductAttention: B=4 H=8 S=2048 D=16, fp32 in/out.
// out = softmax(mask ? -1e10 : 10*tanh(SCALE*(Q K^T))) V
//
// Round 8 = Round 5 hot-loop scheduling restored + two structural changes:
//  * tail guard ONLY in the last round (rounds 0..nr-2 are provably full
//    since nr = ceil(nt/16)) — R7 guarded every tile and regressed ~4us
//    from the 8 uniform branches/round fencing the unrolled body.
//  * denominator on the MFMA pipe: acc2 = mfma(pf, ones, acc2) gives
//    C2[q][d] = sum_key P[q][key] in the SAME C-layout as acc -> epilogue
//    is a per-lane divide, no shfl reduction; deletes 2 VALU dot2/tile
//    from the VALU/trans critical path (MFMA pipe is ~12% utilized, free).
// Carried: per-batch compaction of unmasked keys (~50% masked, p=0 exactly,
// denominator unchanged vs reference), wave-level scan (order-free),
// fragment-major f16 K/V ws, conflict-free b128/b64 LDS double buffer,
// 1 barrier/round, p = exp2(fma(c2, rcp(1+exp2(s)), bias)), Q pre-scaled
// by c1 = 2*SCALE*log2(e).

typedef __fp16 h2 __attribute__((ext_vector_type(2)));
typedef __fp16 h4 __attribute__((ext_vector_type(4)));
typedef float  f4 __attribute__((ext_vector_type(4)));
typedef int    i4 __attribute__((ext_vector_type(4)));

#define SEQ 2048
#define NBH 32
#define TPB 128  // max tiles (of 16 keys) per bh
#define KWS_BYTES ((size_t)NBH * TPB * 64 * 8)   // 2 MB
#define VWS_BYTES KWS_BYTES                      // 2 MB
#define BIAS_BYTES ((size_t)4 * SEQ * 4)         // 32 KB
#define IDX_BYTES  ((size_t)4 * SEQ * 4)         // 32 KB
#define META_BYTES 64
#define WS_NEEDED (KWS_BYTES + VWS_BYTES + BIAS_BYTES + IDX_BYTES + META_BYTES)

__device__ __forceinline__ float fast_exp2(float x) {
#if __has_builtin(__builtin_amdgcn_exp2f)
    return __builtin_amdgcn_exp2f(x);
#else
    return exp2f(x);
#endif
}

__device__ __forceinline__ float dot2acc(h2 a, float accv) {
#if __has_builtin(__builtin_amdgcn_fdot2)
    const h2 one = {(__fp16)1.0f, (__fp16)1.0f};
    return __builtin_amdgcn_fdot2(a, one, accv, false);
#else
    return accv + (float)a[0] + (float)a[1];
#endif
}

// ------- scan: one wave per batch, shfl prefix, order-free compaction -------
__global__ __launch_bounds__(64) void attn_scan(
    const int* __restrict__ maskp, int* __restrict__ idxws,
    float* __restrict__ biasws, int* __restrict__ meta)
{
    const int b = blockIdx.x;
    const int t = threadIdx.x;  // 0..63
    const i4* m4 = (const i4*)(maskp + (size_t)b * SEQ);  // 512 int4

    i4 ch[8];
    int cnt = 0;
    #pragma unroll
    for (int j = 0; j < 8; ++j) {
        ch[j] = m4[j * 64 + t];  // coalesced
        #pragma unroll
        for (int e = 0; e < 4; ++e) cnt += (ch[j][e] == 0);
    }
    // wave inclusive scan of cnt
    int incl = cnt;
    #pragma unroll
    for (int off = 1; off < 64; off <<= 1) {
        int src = __shfl_up(incl, off);
        if (t >= off) incl += src;
    }
    const int total = __shfl(incl, 63);
    int pos = incl - cnt;  // exclusive prefix (any consistent order is valid)
    #pragma unroll
    for (int j = 0; j < 8; ++j) {
        #pragma unroll
        for (int e = 0; e < 4; ++e) {
            if (ch[j][e] == 0)
                idxws[(size_t)b * SEQ + pos++] = (j * 64 + t) * 4 + e;
        }
    }
    // bias + pad-idx fill (pads: i >= total; disjoint from kept writes)
    #pragma unroll
    for (int j = 0; j < 32; ++j) {
        const int i = j * 64 + t;
        biasws[(size_t)b * SEQ + i] = (i < total) ? 0.0f : -1.0e30f;
        if (i >= total) idxws[(size_t)b * SEQ + i] = 0;
    }
    if (t == 0) {
        int nt = (total + 15) >> 4;  if (nt < 1) nt = 1;   // 16-key tiles
        int nr = (nt + 15) >> 4;     if (nr < 1) nr = 1;   // 256-key rounds
        meta[b] = nr;
        meta[4 + b] = nt;
    }
}

// -------- gather prep: compacted K,V -> fragment-major f16 (unchanged) --------
__global__ __launch_bounds__(256) void attn_prep(
    const float* __restrict__ Kp, const float* __restrict__ Vp,
    const int* __restrict__ idxws,
    __fp16* __restrict__ Kws, __fp16* __restrict__ Vws)
{
    const int tid = threadIdx.x;
    const int T   = blockIdx.x * 4 + (tid >> 6);  // global tile 0..4095
    const int l   = tid & 63;
    const int bh  = T >> 7;
    const int t   = T & (TPB - 1);
    const int b   = bh >> 3;
    const int c   = l & 15;
    const int g   = l >> 4;
    const size_t base = (size_t)bh * (SEQ * 16);
    const int*   idx  = idxws + (size_t)b * SEQ;

    // K fragment (A operand): lane l holds K[idx[t*16+c]][4g..4g+3]
    {
        const int krow = idx[t * 16 + c];
        f4 kv = *(const f4*)(Kp + base + (size_t)krow * 16 + 4 * g);
        h2 k0 = __builtin_amdgcn_cvt_pkrtz(kv[0], kv[1]);
        h2 k1 = __builtin_amdgcn_cvt_pkrtz(kv[2], kv[3]);
        h4 kh; kh[0] = k0[0]; kh[1] = k0[1]; kh[2] = k1[0]; kh[3] = k1[1];
        *(h4*)(Kws + ((size_t)T * 64 + l) * 4) = kh;
    }
    // V fragment (B operand): lane l holds V[idx[t*16+4g+j]][c], j=0..3
    {
        const int v0 = idx[t * 16 + 4 * g + 0];
        const int v1 = idx[t * 16 + 4 * g + 1];
        const int v2 = idx[t * 16 + 4 * g + 2];
        const int v3 = idx[t * 16 + 4 * g + 3];
        h2 p0 = __builtin_amdgcn_cvt_pkrtz(Vp[base + (size_t)v0 * 16 + c],
                                           Vp[base + (size_t)v1 * 16 + c]);
        h2 p1 = __builtin_amdgcn_cvt_pkrtz(Vp[base + (size_t)v2 * 16 + c],
                                           Vp[base + (size_t)v3 * 16 + c]);
        h4 vh; vh[0] = p0[0]; vh[1] = p0[1]; vh[2] = p1[0]; vh[3] = p1[1];
        *(h4*)(Vws + ((size_t)T * 64 + l) * 4) = vh;
    }
}

// ---- round body: GUARD=false -> branch-free (rounds 0..nr-2) ----
template<bool GUARD>
__device__ __forceinline__ void do_round(
    const _Float16* __restrict__ Kc, const _Float16* __restrict__ Vc,
    const float* __restrict__ Bc, const h4 qfrag, const h4 ones,
    f4& acc, f4& acc2, const int lane, const int g, const int kg,
    const int tilesLeft)
{
    const float c2 = -28.8539008f;  // -20*log2(e)
    #pragma unroll
    for (int j = 0; j < 8; ++j) {
        const int tir = 2 * j + kg;  // tile within round (interleaved groups)
        if (!GUARD || tir < tilesLeft) {
            h4 afrag = *(const h4*)(Kc + tir * 256 + lane * 4);
            f4 s = __builtin_amdgcn_mfma_f32_16x16x16f16(
                afrag, qfrag, (f4){0.f, 0.f, 0.f, 0.f}, 0, 0, 0);

            f4 b4 = *(const f4*)(Bc + tir * 16 + 4 * g);
            float p[4];
            #pragma unroll
            for (int e = 0; e < 4; ++e) {
                float tt = fast_exp2(s[e]);
                float w  = __builtin_amdgcn_rcpf(1.0f + tt);
                p[e] = fast_exp2(__builtin_fmaf(c2, w, b4[e]));
            }
            h2 plo = __builtin_amdgcn_cvt_pkrtz(p[0], p[1]);
            h2 phi = __builtin_amdgcn_cvt_pkrtz(p[2], p[3]);
            h4 pf; pf[0] = plo[0]; pf[1] = plo[1]; pf[2] = phi[0]; pf[3] = phi[1];

            h4 vfrag = *(const h4*)(Vc + tir * 256 + lane * 4);
            acc  = __builtin_amdgcn_mfma_f32_16x16x16f16(pf, vfrag, acc,  0, 0, 0);
            // denominator on the matrix pipe: C2[q][*] = sum_key P[q][key]
            acc2 = __builtin_amdgcn_mfma_f32_16x16x16f16(pf, ones,  acc2, 0, 0, 0);
        }
    }
}

// -------- hot kernel: LDS double buffer, last-round-only tail guard --------
__global__ __launch_bounds__(512, 8) void attn_v8(
    const float* __restrict__ Qp, const __fp16* __restrict__ Kws,
    const __fp16* __restrict__ Vws, const float* __restrict__ biasws,
    const int* __restrict__ meta, float* __restrict__ out)
{
    __shared__ __align__(16) _Float16 Kbuf[2][4096]; // 16 KB
    __shared__ __align__(16) _Float16 Vbuf[2][4096]; // 16 KB
    __shared__ __align__(16) float    Bbuf[2][256];  //  2 KB

    const int bid  = blockIdx.x;
    const int bh   = bid >> 5;
    const int qblk = bid & 31;
    const int b    = bh >> 3;
    const int tid  = threadIdx.x;
    const int wave = tid >> 6;
    const int lane = tid & 63;
    const int qt   = wave & 3;   // q-tile
    const int kg   = wave >> 2;  // key-group: tiles 2j+kg within each round
    const int c    = lane & 15;
    const int g    = lane >> 4;

    const size_t base  = (size_t)bh * (SEQ * 16);
    const int    qbase = qblk * 64 + qt * 16;
    const float  c1 = 1.1047809f;    // 2*SCALE*log2(e)

    const int nr = meta[b];      // rounds of 256 compacted keys (1..8)
    const int nt = meta[4 + b];  // valid 16-key tiles (1..128)

    // Q fragment (B operand): lane holds c1*Q[qbase+c][4g..4g+3]
    h4 qfrag;
    {
        f4 qv = *(const f4*)(Qp + base + (size_t)(qbase + c) * 16 + 4 * g);
        h2 lo = __builtin_amdgcn_cvt_pkrtz(c1 * qv[0], c1 * qv[1]);
        h2 hi = __builtin_amdgcn_cvt_pkrtz(c1 * qv[2], c1 * qv[3]);
        qfrag[0] = lo[0]; qfrag[1] = lo[1]; qfrag[2] = hi[0]; qfrag[3] = hi[1];
    }
    h4 ones;
    ones[0] = (__fp16)1.0f; ones[1] = (__fp16)1.0f;
    ones[2] = (__fp16)1.0f; ones[3] = (__fp16)1.0f;

    // staging: round = 16 tiles * 512B = 8KB = 512 f4; thread -> one f4
    const f4* ksrc = (const f4*)(Kws + (size_t)bh * TPB * 256);
    const f4* vsrc = (const f4*)(Vws + (size_t)bh * TPB * 256);
    const float* bsrc = biasws + (size_t)b * SEQ;

    f4 kpre = ksrc[tid];
    f4 vpre = vsrc[tid];
    float bpre = (tid < 256) ? bsrc[tid] : 0.0f;
    *(f4*)&Kbuf[0][tid * 8] = kpre;
    *(f4*)&Vbuf[0][tid * 8] = vpre;
    if (tid < 256) Bbuf[0][tid] = bpre;
    {
        const int r1 = (1 < nr) ? 1 : (nr - 1);
        kpre = ksrc[r1 * 512 + tid];
        vpre = vsrc[r1 * 512 + tid];
        if (tid < 256) bpre = bsrc[r1 * 256 + tid];
    }
    __syncthreads();

    f4 acc  = {0.f, 0.f, 0.f, 0.f};  // out rows q=qbase+4g+r, col d=c
    f4 acc2 = {0.f, 0.f, 0.f, 0.f};  // denom(q=qbase+4g+r), all cols equal

    for (int r = 0; r < nr; ++r) {
        const int cb = r & 1, nb = cb ^ 1;
        if (r + 1 < nr) {  // publish prefetched round r+1
            *(f4*)&Kbuf[nb][tid * 8] = kpre;
            *(f4*)&Vbuf[nb][tid * 8] = vpre;
            if (tid < 256) Bbuf[nb][tid] = bpre;
        }
        if (r + 2 < nr) {  // issue loads for round r+2
            kpre = ksrc[(r + 2) * 512 + tid];
            vpre = vsrc[(r + 2) * 512 + tid];
            if (tid < 256) bpre = bsrc[(r + 2) * 256 + tid];
        }

        const _Float16* Kc = &Kbuf[cb][0];
        const _Float16* Vc = &Vbuf[cb][0];
        const float*    Bc = &Bbuf[cb][0];

        if (r + 1 < nr) {
            do_round<false>(Kc, Vc, Bc, qfrag, ones, acc, acc2, lane, g, kg, 16);
        } else {
            do_round<true>(Kc, Vc, Bc, qfrag, ones, acc, acc2, lane, g, kg,
                           nt - (r << 4));
        }
        __syncthreads();
    }

    // cross-key-group combine through LDS (reuse Kbuf; last barrier done)
    float* ex = (float*)&Kbuf[0][0];  // need 256*8 = 2048 floats = 8KB, have 16KB
    const int slot = (qt * 64 + lane) * 8;
    if (kg == 1) {
        ex[slot + 0] = acc[0];  ex[slot + 1] = acc[1];
        ex[slot + 2] = acc[2];  ex[slot + 3] = acc[3];
        ex[slot + 4] = acc2[0]; ex[slot + 5] = acc2[1];
        ex[slot + 6] = acc2[2]; ex[slot + 7] = acc2[3];
    }
    __syncthreads();
    if (kg == 0) {
        #pragma unroll
        for (int i = 0; i < 4; ++i) {
            const float denom = acc2[i] + ex[slot + 4 + i];
            out[base + (size_t)(qbase + 4 * g + i) * 16 + c] =
                (acc[i] + ex[slot + i]) / denom;
        }
    }
}

// ---------------- round-3 fallback (ws too small) ----------------
#define KROW 20
#define VROW 520

__global__ __launch_bounds__(512, 8) void attn_fwd_v3(
    const float* __restrict__ Qp, const float* __restrict__ Kp,
    const float* __restrict__ Vp, const int* __restrict__ maskp,
    float* __restrict__ out)
{
    __shared__ __align__(16) _Float16 Klds[512 * KROW];
    __shared__ __align__(16) _Float16 Vt[16 * VROW];
    __shared__ __align__(16) float biasf[512];

    const int bid  = blockIdx.x;
    const int bh   = bid >> 5;
    const int qblk = bid & 31;
    const int b    = bh >> 3;
    const int tid  = threadIdx.x;
    const int wave = tid >> 6;
    const int lane = tid & 63;
    const int qt   = wave & 3;
    const int kg   = wave >> 2;
    const int c    = lane & 15;
    const int g    = lane >> 4;

    const size_t base = (size_t)bh * (SEQ * 16);
    const int qbase = qblk * 64 + qt * 16;
    const float c1 = 1.1047809f;
    const float c2 = -28.8539008f;

    h4 qfrag;
    {
        f4 qv = *(const f4*)(Qp + base + (size_t)(qbase + c) * 16 + 4 * g);
        h2 lo = __builtin_amdgcn_cvt_pkrtz(c1 * qv[0], c1 * qv[1]);
        h2 hi = __builtin_amdgcn_cvt_pkrtz(c1 * qv[2], c1 * qv[3]);
        qfrag[0] = lo[0]; qfrag[1] = lo[1]; qfrag[2] = hi[0]; qfrag[3] = hi[1];
    }

    f4 acc = {0.f, 0.f, 0.f, 0.f};
    float dsum = 0.f;
    const int kgb = kg * 256;

    for (int round = 0; round < 4; ++round) {
        {
            const float* Kc = Kp + base + (size_t)round * (512 * 16);
            const float* Vc = Vp + base + (size_t)round * (512 * 16);
            #pragma unroll
            for (int j = 0; j < 4; ++j) {
                const int i = j * 512 + tid;
                f4 kv = *(const f4*)(Kc + (size_t)i * 4);
                f4 vv = *(const f4*)(Vc + (size_t)i * 4);
                const int key = i >> 2;
                const int dq  = (i & 3) * 4;
                h2 k0 = __builtin_amdgcn_cvt_pkrtz(kv[0], kv[1]);
                h2 k1 = __builtin_amdgcn_cvt_pkrtz(kv[2], kv[3]);
                h4 kh; kh[0] = k0[0]; kh[1] = k0[1]; kh[2] = k1[0]; kh[3] = k1[1];
                *(h4*)&Klds[key * KROW + dq] = kh;
                #pragma unroll
                for (int e = 0; e < 4; ++e)
                    Vt[(dq + e) * VROW + key] = (_Float16)vv[e];
            }
            biasf[tid] = maskp[(size_t)b * SEQ + round * 512 + tid] ? -60.0f : 0.0f;
        }
        __syncthreads();

        #pragma unroll
        for (int t = 0; t < 16; ++t) {
            const int kb = kgb + t * 16;
            h4 afrag = *(const h4*)&Klds[(kb + c) * KROW + 4 * g];
            f4 s = __builtin_amdgcn_mfma_f32_16x16x16f16(
                afrag, qfrag, (f4){0.f, 0.f, 0.f, 0.f}, 0, 0, 0);
            f4 b4 = *(const f4*)&biasf[kb + 4 * g];
            float p[4];
            #pragma unroll
            for (int i = 0; i < 4; ++i) {
                float tt = fast_exp2(s[i]);
                float w  = __builtin_amdgcn_rcpf(1.0f + tt);
                p[i] = fast_exp2(__builtin_fmaf(c2, w, b4[i]));
            }
            h2 plo = __builtin_amdgcn_cvt_pkrtz(p[0], p[1]);
            h2 phi = __builtin_amdgcn_cvt_pkrtz(p[2], p[3]);
            dsum = dot2acc(plo, dsum);
            dsum = dot2acc(phi, dsum);
            h4 pf; pf[0] = plo[0]; pf[1] = plo[1]; pf[2] = phi[0]; pf[3] = phi[1];
            h4 vfrag = *(const h4*)&Vt[c * VROW + kb + 4 * g];
            acc = __builtin_amdgcn_mfma_f32_16x16x16f16(pf, vfrag, acc, 0, 0, 0);
        }
        __syncthreads();
    }

    dsum += __shfl_xor(dsum, 16);
    dsum += __shfl_xor(dsum, 32);

    float* ex = (float*)Klds;
    const int slot = (qt * 64 + lane) * 5;
    if (kg == 1) {
        ex[slot + 0] = acc[0]; ex[slot + 1] = acc[1];
        ex[slot + 2] = acc[2]; ex[slot + 3] = acc[3];
        ex[slot + 4] = dsum;
    }
    __syncthreads();
    if (kg == 0) {
        const float dT = dsum + ex[slot + 4];
        #pragma unroll
        for (int i = 0; i < 4; ++i) {
            const float denom = __shfl(dT, 4 * g + i);
            out[base + (size_t)(qbase + 4 * g + i) * 16 + c] =
                (acc[i] + ex[slot + i]) / denom;
        }
    }
}

extern "C" void kernel_launch(void* const* d_in, const int* in_sizes, int n_in,
                              void* d_out, int out_size, void* d_ws, size_t ws_size,
                              hipStream_t stream) {
    const float* Q    = (const float*)d_in[0];
    const float* K    = (const float*)d_in[1];
    const float* V    = (const float*)d_in[2];
    const int*   mask = (const int*)d_in[3];
    float* out = (float*)d_out;

    if (ws_size >= WS_NEEDED) {
        char* p = (char*)d_ws;
        __fp16* Kws = (__fp16*)p;                       p += KWS_BYTES;
        __fp16* Vws = (__fp16*)p;                       p += VWS_BYTES;
        float*  Bws = (float*)p;                        p += BIAS_BYTES;
        int*    Iws = (int*)p;                          p += IDX_BYTES;
        int*    Mws = (int*)p;
        attn_scan<<<dim3(4), dim3(64), 0, stream>>>(mask, Iws, Bws, Mws);
        attn_prep<<<dim3(1024), dim3(256), 0, stream>>>(K, V, Iws, Kws, Vws);
        attn_v8<<<dim3(1024), dim3(512), 0, stream>>>(Q, Kws, Vws, Bws, Mws, out);
    } else {
        attn_fwd_v3<<<dim3(1024), dim3(512), 0, stream>>>(Q, K, V, mask, out);
    }
}

// Round 9
// 95.053 us; speedup vs baseline: 1.0234x; 1.0234x over previous
//
#include <hip/hip_runtime.h>

// DotProductAttention: B=4 H=8 S=2048 D=16, fp32 in/out.
// out = softmax(mask ? -1e10 : 10*tanh(SCALE*(Q K^T))) V
//
// Round 9 = EXACT Round-5 hot kernel (93.4us best) + two confined changes:
//  * last-round-ONLY tail guard (rounds 0..nr-2 compile to the identical R5
//    branch-free body; R7 proved guarding every round fences the scheduler).
//    Pads have p=0 exactly, so skipping them is numerically exact.
//  * wave-level scan (shfl prefix, no barriers) instead of 256-thread
//    Hillis-Steele; compacted key order is irrelevant (sums are
//    permutation-invariant).
// REVERTED from R7/R8 (both regressed vs R5): kg-interleaved tile order,
// MFMA-pipe denominator (costs ~= the 2 dot2 it replaces + regalloc damage).
// Carried from R5: per-batch compaction of unmasked keys (~50% masked, p=0
// exactly, denominator unchanged vs reference), fragment-major f16 K/V ws,
// conflict-free b128/b64 LDS double buffer, 1 barrier/round,
// p = exp2(fma(c2, rcp(1+exp2(s)), bias)), Q pre-scaled by c1.

typedef __fp16 h2 __attribute__((ext_vector_type(2)));
typedef __fp16 h4 __attribute__((ext_vector_type(4)));
typedef float  f4 __attribute__((ext_vector_type(4)));
typedef int    i4 __attribute__((ext_vector_type(4)));

#define SEQ 2048
#define NBH 32
#define TPB 128  // max tiles (of 16 keys) per bh
#define KWS_BYTES ((size_t)NBH * TPB * 64 * 8)   // 2 MB
#define VWS_BYTES KWS_BYTES                      // 2 MB
#define BIAS_BYTES ((size_t)4 * SEQ * 4)         // 32 KB
#define IDX_BYTES  ((size_t)4 * SEQ * 4)         // 32 KB
#define META_BYTES 64
#define WS_NEEDED (KWS_BYTES + VWS_BYTES + BIAS_BYTES + IDX_BYTES + META_BYTES)

__device__ __forceinline__ float fast_exp2(float x) {
#if __has_builtin(__builtin_amdgcn_exp2f)
    return __builtin_amdgcn_exp2f(x);
#else
    return exp2f(x);
#endif
}

__device__ __forceinline__ float dot2acc(h2 a, float accv) {
#if __has_builtin(__builtin_amdgcn_fdot2)
    const h2 one = {(__fp16)1.0f, (__fp16)1.0f};
    return __builtin_amdgcn_fdot2(a, one, accv, false);
#else
    return accv + (float)a[0] + (float)a[1];
#endif
}

// ------- scan: one wave per batch, shfl prefix, order-free compaction -------
__global__ __launch_bounds__(64) void attn_scan(
    const int* __restrict__ maskp, int* __restrict__ idxws,
    float* __restrict__ biasws, int* __restrict__ meta)
{
    const int b = blockIdx.x;
    const int t = threadIdx.x;  // 0..63
    const i4* m4 = (const i4*)(maskp + (size_t)b * SEQ);  // 512 int4

    i4 ch[8];
    int cnt = 0;
    #pragma unroll
    for (int j = 0; j < 8; ++j) {
        ch[j] = m4[j * 64 + t];  // coalesced
        #pragma unroll
        for (int e = 0; e < 4; ++e) cnt += (ch[j][e] == 0);
    }
    // wave inclusive scan of cnt
    int incl = cnt;
    #pragma unroll
    for (int off = 1; off < 64; off <<= 1) {
        int src = __shfl_up(incl, off);
        if (t >= off) incl += src;
    }
    const int total = __shfl(incl, 63);
    int pos = incl - cnt;  // exclusive prefix (any consistent order is valid)
    #pragma unroll
    for (int j = 0; j < 8; ++j) {
        #pragma unroll
        for (int e = 0; e < 4; ++e) {
            if (ch[j][e] == 0)
                idxws[(size_t)b * SEQ + pos++] = (j * 64 + t) * 4 + e;
        }
    }
    // bias + pad-idx fill (pads: i >= total; disjoint from kept writes)
    #pragma unroll
    for (int j = 0; j < 32; ++j) {
        const int i = j * 64 + t;
        biasws[(size_t)b * SEQ + i] = (i < total) ? 0.0f : -1.0e30f;
        if (i >= total) idxws[(size_t)b * SEQ + i] = 0;
    }
    if (t == 0) {
        int nt = (total + 15) >> 4;  if (nt < 1) nt = 1;   // 16-key tiles
        int nr = (nt + 15) >> 4;     if (nr < 1) nr = 1;   // 256-key rounds
        meta[b] = nr;
        meta[4 + b] = nt;
    }
}

// -------- gather prep: compacted K,V -> fragment-major f16 (unchanged) --------
__global__ __launch_bounds__(256) void attn_prep(
    const float* __restrict__ Kp, const float* __restrict__ Vp,
    const int* __restrict__ idxws,
    __fp16* __restrict__ Kws, __fp16* __restrict__ Vws)
{
    const int tid = threadIdx.x;
    const int T   = blockIdx.x * 4 + (tid >> 6);  // global tile 0..4095
    const int l   = tid & 63;
    const int bh  = T >> 7;
    const int t   = T & (TPB - 1);
    const int b   = bh >> 3;
    const int c   = l & 15;
    const int g   = l >> 4;
    const size_t base = (size_t)bh * (SEQ * 16);
    const int*   idx  = idxws + (size_t)b * SEQ;

    // K fragment (A operand): lane l holds K[idx[t*16+c]][4g..4g+3]
    {
        const int krow = idx[t * 16 + c];
        f4 kv = *(const f4*)(Kp + base + (size_t)krow * 16 + 4 * g);
        h2 k0 = __builtin_amdgcn_cvt_pkrtz(kv[0], kv[1]);
        h2 k1 = __builtin_amdgcn_cvt_pkrtz(kv[2], kv[3]);
        h4 kh; kh[0] = k0[0]; kh[1] = k0[1]; kh[2] = k1[0]; kh[3] = k1[1];
        *(h4*)(Kws + ((size_t)T * 64 + l) * 4) = kh;
    }
    // V fragment (B operand): lane l holds V[idx[t*16+4g+j]][c], j=0..3
    {
        const int v0 = idx[t * 16 + 4 * g + 0];
        const int v1 = idx[t * 16 + 4 * g + 1];
        const int v2 = idx[t * 16 + 4 * g + 2];
        const int v3 = idx[t * 16 + 4 * g + 3];
        h2 p0 = __builtin_amdgcn_cvt_pkrtz(Vp[base + (size_t)v0 * 16 + c],
                                           Vp[base + (size_t)v1 * 16 + c]);
        h2 p1 = __builtin_amdgcn_cvt_pkrtz(Vp[base + (size_t)v2 * 16 + c],
                                           Vp[base + (size_t)v3 * 16 + c]);
        h4 vh; vh[0] = p0[0]; vh[1] = p0[1]; vh[2] = p1[0]; vh[3] = p1[1];
        *(h4*)(Vws + ((size_t)T * 64 + l) * 4) = vh;
    }
}

// -------- hot kernel: R5 body verbatim + last-round-only tail guard --------
__global__ __launch_bounds__(512, 8) void attn_v9(
    const float* __restrict__ Qp, const __fp16* __restrict__ Kws,
    const __fp16* __restrict__ Vws, const float* __restrict__ biasws,
    const int* __restrict__ meta, float* __restrict__ out)
{
    __shared__ __align__(16) _Float16 Kbuf[2][4096]; // 16 KB
    __shared__ __align__(16) _Float16 Vbuf[2][4096]; // 16 KB
    __shared__ __align__(16) float    Bbuf[2][256];  //  2 KB

    const int bid  = blockIdx.x;
    const int bh   = bid >> 5;
    const int qblk = bid & 31;
    const int b    = bh >> 3;
    const int tid  = threadIdx.x;
    const int wave = tid >> 6;
    const int lane = tid & 63;
    const int qt   = wave & 3;   // q-tile
    const int kg   = wave >> 2;  // key-group: tiles kg*8 + t (contiguous, R5)
    const int c    = lane & 15;
    const int g    = lane >> 4;

    const size_t base  = (size_t)bh * (SEQ * 16);
    const int    qbase = qblk * 64 + qt * 16;
    const float  c1 = 1.1047809f;    // 2*SCALE*log2(e)
    const float  c2 = -28.8539008f;  // -20*log2(e)

    const int nr = meta[b];      // rounds of 256 compacted keys (1..8)
    const int nt = meta[4 + b];  // valid 16-key tiles (1..128)

    // Q fragment (B operand): lane holds c1*Q[qbase+c][4g..4g+3]
    h4 qfrag;
    {
        f4 qv = *(const f4*)(Qp + base + (size_t)(qbase + c) * 16 + 4 * g);
        h2 lo = __builtin_amdgcn_cvt_pkrtz(c1 * qv[0], c1 * qv[1]);
        h2 hi = __builtin_amdgcn_cvt_pkrtz(c1 * qv[2], c1 * qv[3]);
        qfrag[0] = lo[0]; qfrag[1] = lo[1]; qfrag[2] = hi[0]; qfrag[3] = hi[1];
    }

    // staging: round = 16 tiles * 512B = 8KB = 512 f4; thread -> one f4
    const f4* ksrc = (const f4*)(Kws + (size_t)bh * TPB * 256);
    const f4* vsrc = (const f4*)(Vws + (size_t)bh * TPB * 256);
    const float* bsrc = biasws + (size_t)b * SEQ;

    f4 kpre = ksrc[tid];
    f4 vpre = vsrc[tid];
    float bpre = (tid < 256) ? bsrc[tid] : 0.0f;
    *(f4*)&Kbuf[0][tid * 8] = kpre;
    *(f4*)&Vbuf[0][tid * 8] = vpre;
    if (tid < 256) Bbuf[0][tid] = bpre;
    {
        const int r1 = (1 < nr) ? 1 : (nr - 1);
        kpre = ksrc[r1 * 512 + tid];
        vpre = vsrc[r1 * 512 + tid];
        if (tid < 256) bpre = bsrc[r1 * 256 + tid];
    }
    __syncthreads();

    f4 acc = {0.f, 0.f, 0.f, 0.f};
    float dsum = 0.f;

    for (int r = 0; r < nr; ++r) {
        const int cb = r & 1, nb = cb ^ 1;
        if (r + 1 < nr) {  // publish prefetched round r+1
            *(f4*)&Kbuf[nb][tid * 8] = kpre;
            *(f4*)&Vbuf[nb][tid * 8] = vpre;
            if (tid < 256) Bbuf[nb][tid] = bpre;
        }
        if (r + 2 < nr) {  // issue loads for round r+2
            kpre = ksrc[(r + 2) * 512 + tid];
            vpre = vsrc[(r + 2) * 512 + tid];
            if (tid < 256) bpre = bsrc[(r + 2) * 256 + tid];
        }

        const _Float16* Kc = &Kbuf[cb][kg * 2048];
        const _Float16* Vc = &Vbuf[cb][kg * 2048];
        const float*    Bc = &Bbuf[cb][kg * 128];

        if (r + 1 < nr) {
            // ---- full round: EXACT R5 branch-free body ----
            #pragma unroll
            for (int t = 0; t < 8; ++t) {
                h4 afrag = *(const h4*)(Kc + t * 256 + lane * 4);
                f4 s = __builtin_amdgcn_mfma_f32_16x16x16f16(
                    afrag, qfrag, (f4){0.f, 0.f, 0.f, 0.f}, 0, 0, 0);

                f4 b4 = *(const f4*)(Bc + t * 16 + 4 * g);
                float p[4];
                #pragma unroll
                for (int e = 0; e < 4; ++e) {
                    float tt = fast_exp2(s[e]);
                    float w  = __builtin_amdgcn_rcpf(1.0f + tt);
                    p[e] = fast_exp2(__builtin_fmaf(c2, w, b4[e]));
                }
                h2 plo = __builtin_amdgcn_cvt_pkrtz(p[0], p[1]);
                h2 phi = __builtin_amdgcn_cvt_pkrtz(p[2], p[3]);
                dsum = dot2acc(plo, dsum);
                dsum = dot2acc(phi, dsum);
                h4 pf; pf[0] = plo[0]; pf[1] = plo[1]; pf[2] = phi[0]; pf[3] = phi[1];

                h4 vfrag = *(const h4*)(Vc + t * 256 + lane * 4);
                acc = __builtin_amdgcn_mfma_f32_16x16x16f16(pf, vfrag, acc, 0, 0, 0);
            }
        } else {
            // ---- last round: same body, wave-uniform tile guard ----
            const int tilesLeft = nt - (r << 4);  // 1..16
            #pragma unroll
            for (int t = 0; t < 8; ++t) {
                if (kg * 8 + t < tilesLeft) {
                    h4 afrag = *(const h4*)(Kc + t * 256 + lane * 4);
                    f4 s = __builtin_amdgcn_mfma_f32_16x16x16f16(
                        afrag, qfrag, (f4){0.f, 0.f, 0.f, 0.f}, 0, 0, 0);

                    f4 b4 = *(const f4*)(Bc + t * 16 + 4 * g);
                    float p[4];
                    #pragma unroll
                    for (int e = 0; e < 4; ++e) {
                        float tt = fast_exp2(s[e]);
                        float w  = __builtin_amdgcn_rcpf(1.0f + tt);
                        p[e] = fast_exp2(__builtin_fmaf(c2, w, b4[e]));
                    }
                    h2 plo = __builtin_amdgcn_cvt_pkrtz(p[0], p[1]);
                    h2 phi = __builtin_amdgcn_cvt_pkrtz(p[2], p[3]);
                    dsum = dot2acc(plo, dsum);
                    dsum = dot2acc(phi, dsum);
                    h4 pf; pf[0] = plo[0]; pf[1] = plo[1]; pf[2] = phi[0]; pf[3] = phi[1];

                    h4 vfrag = *(const h4*)(Vc + t * 256 + lane * 4);
                    acc = __builtin_amdgcn_mfma_f32_16x16x16f16(pf, vfrag, acc, 0, 0, 0);
                }
            }
        }
        __syncthreads();
    }

    // denom over this key-group for q=qbase+c, on all lanes of the wave
    dsum += __shfl_xor(dsum, 16);
    dsum += __shfl_xor(dsum, 32);

    // cross-key-group combine through LDS (reuse Kbuf; last barrier done)
    float* ex = (float*)&Kbuf[0][0];
    const int slot = (qt * 64 + lane) * 5;
    if (kg == 1) {
        ex[slot + 0] = acc[0]; ex[slot + 1] = acc[1];
        ex[slot + 2] = acc[2]; ex[slot + 3] = acc[3];
        ex[slot + 4] = dsum;
    }
    __syncthreads();
    if (kg == 0) {
        const float dT = dsum + ex[slot + 4];
        #pragma unroll
        for (int i = 0; i < 4; ++i) {
            const float denom = __shfl(dT, 4 * g + i);
            out[base + (size_t)(qbase + 4 * g + i) * 16 + c] =
                (acc[i] + ex[slot + i]) / denom;
        }
    }
}

// ---------------- round-3 fallback (ws too small) ----------------
#define KROW 20
#define VROW 520

__global__ __launch_bounds__(512, 8) void attn_fwd_v3(
    const float* __restrict__ Qp, const float* __restrict__ Kp,
    const float* __restrict__ Vp, const int* __restrict__ maskp,
    float* __restrict__ out)
{
    __shared__ __align__(16) _Float16 Klds[512 * KROW];
    __shared__ __align__(16) _Float16 Vt[16 * VROW];
    __shared__ __align__(16) float biasf[512];

    const int bid  = blockIdx.x;
    const int bh   = bid >> 5;
    const int qblk = bid & 31;
    const int b    = bh >> 3;
    const int tid  = threadIdx.x;
    const int wave = tid >> 6;
    const int lane = tid & 63;
    const int qt   = wave & 3;
    const int kg   = wave >> 2;
    const int c    = lane & 15;
    const int g    = lane >> 4;

    const size_t base = (size_t)bh * (SEQ * 16);
    const int qbase = qblk * 64 + qt * 16;
    const float c1 = 1.1047809f;
    const float c2 = -28.8539008f;

    h4 qfrag;
    {
        f4 qv = *(const f4*)(Qp + base + (size_t)(qbase + c) * 16 + 4 * g);
        h2 lo = __builtin_amdgcn_cvt_pkrtz(c1 * qv[0], c1 * qv[1]);
        h2 hi = __builtin_amdgcn_cvt_pkrtz(c1 * qv[2], c1 * qv[3]);
        qfrag[0] = lo[0]; qfrag[1] = lo[1]; qfrag[2] = hi[0]; qfrag[3] = hi[1];
    }

    f4 acc = {0.f, 0.f, 0.f, 0.f};
    float dsum = 0.f;
    const int kgb = kg * 256;

    for (int round = 0; round < 4; ++round) {
        {
            const float* Kc = Kp + base + (size_t)round * (512 * 16);
            const float* Vc = Vp + base + (size_t)round * (512 * 16);
            #pragma unroll
            for (int j = 0; j < 4; ++j) {
                const int i = j * 512 + tid;
                f4 kv = *(const f4*)(Kc + (size_t)i * 4);
                f4 vv = *(const f4*)(Vc + (size_t)i * 4);
                const int key = i >> 2;
                const int dq  = (i & 3) * 4;
                h2 k0 = __builtin_amdgcn_cvt_pkrtz(kv[0], kv[1]);
                h2 k1 = __builtin_amdgcn_cvt_pkrtz(kv[2], kv[3]);
                h4 kh; kh[0] = k0[0]; kh[1] = k0[1]; kh[2] = k1[0]; kh[3] = k1[1];
                *(h4*)&Klds[key * KROW + dq] = kh;
                #pragma unroll
                for (int e = 0; e < 4; ++e)
                    Vt[(dq + e) * VROW + key] = (_Float16)vv[e];
            }
            biasf[tid] = maskp[(size_t)b * SEQ + round * 512 + tid] ? -60.0f : 0.0f;
        }
        __syncthreads();

        #pragma unroll
        for (int t = 0; t < 16; ++t) {
            const int kb = kgb + t * 16;
            h4 afrag = *(const h4*)&Klds[(kb + c) * KROW + 4 * g];
            f4 s = __builtin_amdgcn_mfma_f32_16x16x16f16(
                afrag, qfrag, (f4){0.f, 0.f, 0.f, 0.f}, 0, 0, 0);
            f4 b4 = *(const f4*)&biasf[kb + 4 * g];
            float p[4];
            #pragma unroll
            for (int i = 0; i < 4; ++i) {
                float tt = fast_exp2(s[i]);
                float w  = __builtin_amdgcn_rcpf(1.0f + tt);
                p[i] = fast_exp2(__builtin_fmaf(c2, w, b4[i]));
            }
            h2 plo = __builtin_amdgcn_cvt_pkrtz(p[0], p[1]);
            h2 phi = __builtin_amdgcn_cvt_pkrtz(p[2], p[3]);
            dsum = dot2acc(plo, dsum);
            dsum = dot2acc(phi, dsum);
            h4 pf; pf[0] = plo[0]; pf[1] = plo[1]; pf[2] = phi[0]; pf[3] = phi[1];
            h4 vfrag = *(const h4*)&Vt[c * VROW + kb + 4 * g];
            acc = __builtin_amdgcn_mfma_f32_16x16x16f16(pf, vfrag, acc, 0, 0, 0);
        }
        __syncthreads();
    }

    dsum += __shfl_xor(dsum, 16);
    dsum += __shfl_xor(dsum, 32);

    float* ex = (float*)Klds;
    const int slot = (qt * 64 + lane) * 5;
    if (kg == 1) {
        ex[slot + 0] = acc[0]; ex[slot + 1] = acc[1];
        ex[slot + 2] = acc[2]; ex[slot + 3] = acc[3];
        ex[slot + 4] = dsum;
    }
    __syncthreads();
    if (kg == 0) {
        const float dT = dsum + ex[slot + 4];
        #pragma unroll
        for (int i = 0; i < 4; ++i) {
            const float denom = __shfl(dT, 4 * g + i);
            out[base + (size_t)(qbase + 4 * g + i) * 16 + c] =
                (acc[i] + ex[slot + i]) / denom;
        }
    }
}

extern "C" void kernel_launch(void* const* d_in, const int* in_sizes, int n_in,
                              void* d_out, int out_size, void* d_ws, size_t ws_size,
                              hipStream_t stream) {
    const float* Q    = (const float*)d_in[0];
    const float* K    = (const float*)d_in[1];
    const float* V    = (const float*)d_in[2];
    const int*   mask = (const int*)d_in[3];
    float* out = (float*)d_out;

    if (ws_size >= WS_NEEDED) {
        char* p = (char*)d_ws;
        __fp16* Kws = (__fp16*)p;                       p += KWS_BYTES;
        __fp16* Vws = (__fp16*)p;                       p += VWS_BYTES;
        float*  Bws = (float*)p;                        p += BIAS_BYTES;
        int*    Iws = (int*)p;                          p += IDX_BYTES;
        int*    Mws = (int*)p;
        attn_scan<<<dim3(4), dim3(64), 0, stream>>>(mask, Iws, Bws, Mws);
        attn_prep<<<dim3(1024), dim3(256), 0, stream>>>(K, V, Iws, Kws, Vws);
        attn_v9<<<dim3(1024), dim3(512), 0, stream>>>(Q, Kws, Vws, Bws, Mws, out);
    } else {
        attn_fwd_v3<<<dim3(1024), dim3(512), 0, stream>>>(Q, K, V, mask, out);
    }
}

// Round 10
// 94.252 us; speedup vs baseline: 1.0321x; 1.0085x over previous
//
#include <hip/hip_runtime.h>

// DotProductAttention: B=4 H=8 S=2048 D=16, fp32 in/out.
// out = softmax(mask ? -1e10 : 10*tanh(SCALE*(Q K^T))) V
//
// Round 10 = convergence: EXACT Round-5 hot kernel (best measured, 93.4us)
// + wave-level scan (strictly fewer barriers; touches nothing hot).
// NO tail guard anywhere — R7 (guard all rounds), R8 (interleave + MFMA
// denominator), R9 (last-round-only guard) ALL regressed vs the plain R5
// branch-free schedule; the compiler's interleaving of MFMA/trans/ds_read
// across the unrolled 8-tile body is worth more than the ~11% pad-work the
// guards tried to skip.
// Structure: scan (per-batch compaction of unmasked keys — ~50% are masked
// and contribute p=0 EXACTLY, so the denominator matches the fp32 reference,
// which also underflows exp(-1e10)) -> gather-prep (compacted K,V into
// MFMA-fragment-major f16 tiles) -> hot kernel (dynamic 1..8 rounds of 256
// keys, conflict-free b128/b64 LDS double buffer, 1 barrier/round,
// p = exp2(fma(c2, rcp(1+exp2(s)), bias)) with Q pre-scaled by
// c1 = 2*SCALE*log2(e): 3 trans + 2 VALU per softmax element).

typedef __fp16 h2 __attribute__((ext_vector_type(2)));
typedef __fp16 h4 __attribute__((ext_vector_type(4)));
typedef float  f4 __attribute__((ext_vector_type(4)));
typedef int    i4 __attribute__((ext_vector_type(4)));

#define SEQ 2048
#define NBH 32
#define TPB 128  // max tiles (of 16 keys) per bh
#define KWS_BYTES ((size_t)NBH * TPB * 64 * 8)   // 2 MB
#define VWS_BYTES KWS_BYTES                      // 2 MB
#define BIAS_BYTES ((size_t)4 * SEQ * 4)         // 32 KB
#define IDX_BYTES  ((size_t)4 * SEQ * 4)         // 32 KB
#define META_BYTES 64
#define WS_NEEDED (KWS_BYTES + VWS_BYTES + BIAS_BYTES + IDX_BYTES + META_BYTES)

__device__ __forceinline__ float fast_exp2(float x) {
#if __has_builtin(__builtin_amdgcn_exp2f)
    return __builtin_amdgcn_exp2f(x);
#else
    return exp2f(x);
#endif
}

__device__ __forceinline__ float dot2acc(h2 a, float accv) {
#if __has_builtin(__builtin_amdgcn_fdot2)
    const h2 one = {(__fp16)1.0f, (__fp16)1.0f};
    return __builtin_amdgcn_fdot2(a, one, accv, false);
#else
    return accv + (float)a[0] + (float)a[1];
#endif
}

// ------- scan: one wave per batch, shfl prefix, order-free compaction -------
__global__ __launch_bounds__(64) void attn_scan(
    const int* __restrict__ maskp, int* __restrict__ idxws,
    float* __restrict__ biasws, int* __restrict__ meta)
{
    const int b = blockIdx.x;
    const int t = threadIdx.x;  // 0..63
    const i4* m4 = (const i4*)(maskp + (size_t)b * SEQ);  // 512 int4

    i4 ch[8];
    int cnt = 0;
    #pragma unroll
    for (int j = 0; j < 8; ++j) {
        ch[j] = m4[j * 64 + t];  // coalesced
        #pragma unroll
        for (int e = 0; e < 4; ++e) cnt += (ch[j][e] == 0);
    }
    // wave inclusive scan of cnt
    int incl = cnt;
    #pragma unroll
    for (int off = 1; off < 64; off <<= 1) {
        int src = __shfl_up(incl, off);
        if (t >= off) incl += src;
    }
    const int total = __shfl(incl, 63);
    int pos = incl - cnt;  // exclusive prefix (any consistent order is valid)
    #pragma unroll
    for (int j = 0; j < 8; ++j) {
        #pragma unroll
        for (int e = 0; e < 4; ++e) {
            if (ch[j][e] == 0)
                idxws[(size_t)b * SEQ + pos++] = (j * 64 + t) * 4 + e;
        }
    }
    // bias + pad-idx fill (pads: i >= total; disjoint from kept writes)
    #pragma unroll
    for (int j = 0; j < 32; ++j) {
        const int i = j * 64 + t;
        biasws[(size_t)b * SEQ + i] = (i < total) ? 0.0f : -1.0e30f;
        if (i >= total) idxws[(size_t)b * SEQ + i] = 0;
    }
    if (t == 0) {
        int nr = ((total + 255) >> 8);  // 256-key rounds
        meta[b] = nr < 1 ? 1 : nr;
    }
}

// -------- gather prep: compacted K,V -> fragment-major f16 (unchanged) --------
__global__ __launch_bounds__(256) void attn_prep(
    const float* __restrict__ Kp, const float* __restrict__ Vp,
    const int* __restrict__ idxws,
    __fp16* __restrict__ Kws, __fp16* __restrict__ Vws)
{
    const int tid = threadIdx.x;
    const int T   = blockIdx.x * 4 + (tid >> 6);  // global tile 0..4095
    const int l   = tid & 63;
    const int bh  = T >> 7;
    const int t   = T & (TPB - 1);
    const int b   = bh >> 3;
    const int c   = l & 15;
    const int g   = l >> 4;
    const size_t base = (size_t)bh * (SEQ * 16);
    const int*   idx  = idxws + (size_t)b * SEQ;

    // K fragment (A operand): lane l holds K[idx[t*16+c]][4g..4g+3]
    {
        const int krow = idx[t * 16 + c];
        f4 kv = *(const f4*)(Kp + base + (size_t)krow * 16 + 4 * g);
        h2 k0 = __builtin_amdgcn_cvt_pkrtz(kv[0], kv[1]);
        h2 k1 = __builtin_amdgcn_cvt_pkrtz(kv[2], kv[3]);
        h4 kh; kh[0] = k0[0]; kh[1] = k0[1]; kh[2] = k1[0]; kh[3] = k1[1];
        *(h4*)(Kws + ((size_t)T * 64 + l) * 4) = kh;
    }
    // V fragment (B operand): lane l holds V[idx[t*16+4g+j]][c], j=0..3
    {
        const int v0 = idx[t * 16 + 4 * g + 0];
        const int v1 = idx[t * 16 + 4 * g + 1];
        const int v2 = idx[t * 16 + 4 * g + 2];
        const int v3 = idx[t * 16 + 4 * g + 3];
        h2 p0 = __builtin_amdgcn_cvt_pkrtz(Vp[base + (size_t)v0 * 16 + c],
                                           Vp[base + (size_t)v1 * 16 + c]);
        h2 p1 = __builtin_amdgcn_cvt_pkrtz(Vp[base + (size_t)v2 * 16 + c],
                                           Vp[base + (size_t)v3 * 16 + c]);
        h4 vh; vh[0] = p0[0]; vh[1] = p0[1]; vh[2] = p1[0]; vh[3] = p1[1];
        *(h4*)(Vws + ((size_t)T * 64 + l) * 4) = vh;
    }
}

// -------- hot kernel: EXACT R5 body (best measured schedule) --------
__global__ __launch_bounds__(512, 8) void attn_v10(
    const float* __restrict__ Qp, const __fp16* __restrict__ Kws,
    const __fp16* __restrict__ Vws, const float* __restrict__ biasws,
    const int* __restrict__ meta, float* __restrict__ out)
{
    __shared__ __align__(16) _Float16 Kbuf[2][4096]; // 16 KB
    __shared__ __align__(16) _Float16 Vbuf[2][4096]; // 16 KB
    __shared__ __align__(16) float    Bbuf[2][256];  //  2 KB

    const int bid  = blockIdx.x;
    const int bh   = bid >> 5;
    const int qblk = bid & 31;
    const int b    = bh >> 3;
    const int tid  = threadIdx.x;
    const int wave = tid >> 6;
    const int lane = tid & 63;
    const int qt   = wave & 3;   // q-tile
    const int kg   = wave >> 2;  // key-group (tiles 0..7 vs 8..15 of a round)
    const int c    = lane & 15;
    const int g    = lane >> 4;

    const size_t base  = (size_t)bh * (SEQ * 16);
    const int    qbase = qblk * 64 + qt * 16;
    const float  c1 = 1.1047809f;    // 2*SCALE*log2(e)
    const float  c2 = -28.8539008f;  // -20*log2(e)

    const int nr = meta[b];          // rounds of 256 compacted keys (1..8)

    // Q fragment (B operand): lane holds c1*Q[qbase+c][4g..4g+3]
    h4 qfrag;
    {
        f4 qv = *(const f4*)(Qp + base + (size_t)(qbase + c) * 16 + 4 * g);
        h2 lo = __builtin_amdgcn_cvt_pkrtz(c1 * qv[0], c1 * qv[1]);
        h2 hi = __builtin_amdgcn_cvt_pkrtz(c1 * qv[2], c1 * qv[3]);
        qfrag[0] = lo[0]; qfrag[1] = lo[1]; qfrag[2] = hi[0]; qfrag[3] = hi[1];
    }

    // staging: round = 16 tiles * 512B = 8KB = 512 f4; thread -> one f4
    const f4* ksrc = (const f4*)(Kws + (size_t)bh * TPB * 256);
    const f4* vsrc = (const f4*)(Vws + (size_t)bh * TPB * 256);
    const float* bsrc = biasws + (size_t)b * SEQ;

    f4 kpre = ksrc[tid];
    f4 vpre = vsrc[tid];
    float bpre = (tid < 256) ? bsrc[tid] : 0.0f;
    *(f4*)&Kbuf[0][tid * 8] = kpre;
    *(f4*)&Vbuf[0][tid * 8] = vpre;
    if (tid < 256) Bbuf[0][tid] = bpre;
    {
        const int r1 = (1 < nr) ? 1 : (nr - 1);
        kpre = ksrc[r1 * 512 + tid];
        vpre = vsrc[r1 * 512 + tid];
        if (tid < 256) bpre = bsrc[r1 * 256 + tid];
    }
    __syncthreads();

    f4 acc = {0.f, 0.f, 0.f, 0.f};
    float dsum = 0.f;

    for (int r = 0; r < nr; ++r) {
        const int cb = r & 1, nb = cb ^ 1;
        if (r + 1 < nr) {  // publish prefetched round r+1
            *(f4*)&Kbuf[nb][tid * 8] = kpre;
            *(f4*)&Vbuf[nb][tid * 8] = vpre;
            if (tid < 256) Bbuf[nb][tid] = bpre;
        }
        if (r + 2 < nr) {  // issue loads for round r+2
            kpre = ksrc[(r + 2) * 512 + tid];
            vpre = vsrc[(r + 2) * 512 + tid];
            if (tid < 256) bpre = bsrc[(r + 2) * 256 + tid];
        }

        const _Float16* Kc = &Kbuf[cb][kg * 2048];
        const _Float16* Vc = &Vbuf[cb][kg * 2048];
        const float*    Bc = &Bbuf[cb][kg * 128];

        #pragma unroll
        for (int t = 0; t < 8; ++t) {
            h4 afrag = *(const h4*)(Kc + t * 256 + lane * 4);
            f4 s = __builtin_amdgcn_mfma_f32_16x16x16f16(
                afrag, qfrag, (f4){0.f, 0.f, 0.f, 0.f}, 0, 0, 0);

            f4 b4 = *(const f4*)(Bc + t * 16 + 4 * g);
            float p[4];
            #pragma unroll
            for (int e = 0; e < 4; ++e) {
                float tt = fast_exp2(s[e]);
                float w  = __builtin_amdgcn_rcpf(1.0f + tt);
                p[e] = fast_exp2(__builtin_fmaf(c2, w, b4[e]));
            }
            h2 plo = __builtin_amdgcn_cvt_pkrtz(p[0], p[1]);
            h2 phi = __builtin_amdgcn_cvt_pkrtz(p[2], p[3]);
            dsum = dot2acc(plo, dsum);
            dsum = dot2acc(phi, dsum);
            h4 pf; pf[0] = plo[0]; pf[1] = plo[1]; pf[2] = phi[0]; pf[3] = phi[1];

            h4 vfrag = *(const h4*)(Vc + t * 256 + lane * 4);
            acc = __builtin_amdgcn_mfma_f32_16x16x16f16(pf, vfrag, acc, 0, 0, 0);
        }
        __syncthreads();
    }

    // denom over this key-group for q=qbase+c, on all lanes of the wave
    dsum += __shfl_xor(dsum, 16);
    dsum += __shfl_xor(dsum, 32);

    // cross-key-group combine through LDS (reuse Kbuf; last barrier done)
    float* ex = (float*)&Kbuf[0][0];
    const int slot = (qt * 64 + lane) * 5;
    if (kg == 1) {
        ex[slot + 0] = acc[0]; ex[slot + 1] = acc[1];
        ex[slot + 2] = acc[2]; ex[slot + 3] = acc[3];
        ex[slot + 4] = dsum;
    }
    __syncthreads();
    if (kg == 0) {
        const float dT = dsum + ex[slot + 4];
        #pragma unroll
        for (int i = 0; i < 4; ++i) {
            const float denom = __shfl(dT, 4 * g + i);
            out[base + (size_t)(qbase + 4 * g + i) * 16 + c] =
                (acc[i] + ex[slot + i]) / denom;
        }
    }
}

// ---------------- round-3 fallback (ws too small) ----------------
#define KROW 20
#define VROW 520

__global__ __launch_bounds__(512, 8) void attn_fwd_v3(
    const float* __restrict__ Qp, const float* __restrict__ Kp,
    const float* __restrict__ Vp, const int* __restrict__ maskp,
    float* __restrict__ out)
{
    __shared__ __align__(16) _Float16 Klds[512 * KROW];
    __shared__ __align__(16) _Float16 Vt[16 * VROW];
    __shared__ __align__(16) float biasf[512];

    const int bid  = blockIdx.x;
    const int bh   = bid >> 5;
    const int qblk = bid & 31;
    const int b    = bh >> 3;
    const int tid  = threadIdx.x;
    const int wave = tid >> 6;
    const int lane = tid & 63;
    const int qt   = wave & 3;
    const int kg   = wave >> 2;
    const int c    = lane & 15;
    const int g    = lane >> 4;

    const size_t base = (size_t)bh * (SEQ * 16);
    const int qbase = qblk * 64 + qt * 16;
    const float c1 = 1.1047809f;
    const float c2 = -28.8539008f;

    h4 qfrag;
    {
        f4 qv = *(const f4*)(Qp + base + (size_t)(qbase + c) * 16 + 4 * g);
        h2 lo = __builtin_amdgcn_cvt_pkrtz(c1 * qv[0], c1 * qv[1]);
        h2 hi = __builtin_amdgcn_cvt_pkrtz(c1 * qv[2], c1 * qv[3]);
        qfrag[0] = lo[0]; qfrag[1] = lo[1]; qfrag[2] = hi[0]; qfrag[3] = hi[1];
    }

    f4 acc = {0.f, 0.f, 0.f, 0.f};
    float dsum = 0.f;
    const int kgb = kg * 256;

    for (int round = 0; round < 4; ++round) {
        {
            const float* Kc = Kp + base + (size_t)round * (512 * 16);
            const float* Vc = Vp + base + (size_t)round * (512 * 16);
            #pragma unroll
            for (int j = 0; j < 4; ++j) {
                const int i = j * 512 + tid;
                f4 kv = *(const f4*)(Kc + (size_t)i * 4);
                f4 vv = *(const f4*)(Vc + (size_t)i * 4);
                const int key = i >> 2;
                const int dq  = (i & 3) * 4;
                h2 k0 = __builtin_amdgcn_cvt_pkrtz(kv[0], kv[1]);
                h2 k1 = __builtin_amdgcn_cvt_pkrtz(kv[2], kv[3]);
                h4 kh; kh[0] = k0[0]; kh[1] = k0[1]; kh[2] = k1[0]; kh[3] = k1[1];
                *(h4*)&Klds[key * KROW + dq] = kh;
                #pragma unroll
                for (int e = 0; e < 4; ++e)
                    Vt[(dq + e) * VROW + key] = (_Float16)vv[e];
            }
            biasf[tid] = maskp[(size_t)b * SEQ + round * 512 + tid] ? -60.0f : 0.0f;
        }
        __syncthreads();

        #pragma unroll
        for (int t = 0; t < 16; ++t) {
            const int kb = kgb + t * 16;
            h4 afrag = *(const h4*)&Klds[(kb + c) * KROW + 4 * g];
            f4 s = __builtin_amdgcn_mfma_f32_16x16x16f16(
                afrag, qfrag, (f4){0.f, 0.f, 0.f, 0.f}, 0, 0, 0);
            f4 b4 = *(const f4*)&biasf[kb + 4 * g];
            float p[4];
            #pragma unroll
            for (int i = 0; i < 4; ++i) {
                float tt = fast_exp2(s[i]);
                float w  = __builtin_amdgcn_rcpf(1.0f + tt);
                p[i] = fast_exp2(__builtin_fmaf(c2, w, b4[i]));
            }
            h2 plo = __builtin_amdgcn_cvt_pkrtz(p[0], p[1]);
            h2 phi = __builtin_amdgcn_cvt_pkrtz(p[2], p[3]);
            dsum = dot2acc(plo, dsum);
            dsum = dot2acc(phi, dsum);
            h4 pf; pf[0] = plo[0]; pf[1] = plo[1]; pf[2] = phi[0]; pf[3] = phi[1];
            h4 vfrag = *(const h4*)&Vt[c * VROW + kb + 4 * g];
            acc = __builtin_amdgcn_mfma_f32_16x16x16f16(pf, vfrag, acc, 0, 0, 0);
        }
        __syncthreads();
    }

    dsum += __shfl_xor(dsum, 16);
    dsum += __shfl_xor(dsum, 32);

    float* ex = (float*)Klds;
    const int slot = (qt * 64 + lane) * 5;
    if (kg == 1) {
        ex[slot + 0] = acc[0]; ex[slot + 1] = acc[1];
        ex[slot + 2] = acc[2]; ex[slot + 3] = acc[3];
        ex[slot + 4] = dsum;
    }
    __syncthreads();
    if (kg == 0) {
        const float dT = dsum + ex[slot + 4];
        #pragma unroll
        for (int i = 0; i < 4; ++i) {
            const float denom = __shfl(dT, 4 * g + i);
            out[base + (size_t)(qbase + 4 * g + i) * 16 + c] =
                (acc[i] + ex[slot + i]) / denom;
        }
    }
}

extern "C" void kernel_launch(void* const* d_in, const int* in_sizes, int n_in,
                              void* d_out, int out_size, void* d_ws, size_t ws_size,
                              hipStream_t stream) {
    const float* Q    = (const float*)d_in[0];
    const float* K    = (const float*)d_in[1];
    const float* V    = (const float*)d_in[2];
    const int*   mask = (const int*)d_in[3];
    float* out = (float*)d_out;

    if (ws_size >= WS_NEEDED) {
        char* p = (char*)d_ws;
        __fp16* Kws = (__fp16*)p;                       p += KWS_BYTES;
        __fp16* Vws = (__fp16*)p;                       p += VWS_BYTES;
        float*  Bws = (float*)p;                        p += BIAS_BYTES;
        int*    Iws = (int*)p;                          p += IDX_BYTES;
        int*    Mws = (int*)p;
        attn_scan<<<dim3(4), dim3(64), 0, stream>>>(mask, Iws, Bws, Mws);
        attn_prep<<<dim3(1024), dim3(256), 0, stream>>>(K, V, Iws, Kws, Vws);
        attn_v10<<<dim3(1024), dim3(512), 0, stream>>>(Q, Kws, Vws, Bws, Mws, out);
    } else {
        attn_fwd_v3<<<dim3(1024), dim3(512), 0, stream>>>(Q, K, V, mask, out);
    }
}